// Round 8
// baseline (428.320 us; speedup 1.0000x reference)
//
#include <hip/hip_runtime.h>
#include <hip/hip_bf16.h>
#include <cstdint>
#include <cstddef>

// B=64, N=256 leaves, E=D=U=512.
// Outputs: h_new[64*512], c_new[64*512], leaf_h_new[64*256*512] concat flat fp32.

__device__ __forceinline__ float sigmoidf_(float x) { return 1.0f / (1.0f + __expf(-x)); }

typedef __attribute__((ext_vector_type(8))) short bf16x8;
typedef __attribute__((ext_vector_type(4))) float f32x4;

__device__ __forceinline__ void load_lds16b(const void* g, void* l) {
  __builtin_amdgcn_global_load_lds((const __attribute__((address_space(1))) void*)g,
                                   (__attribute__((address_space(3))) void*)l, 16, 0, 0);
}

// ---------- all three weight transposes in one launch ----------
__global__ __launch_bounds__(256)
void tconv_all(const float* __restrict__ W_t, const float* __restrict__ W_j,
               const float* __restrict__ W_h,
               __hip_bfloat16* __restrict__ Wt_t, __hip_bfloat16* __restrict__ Wt_j,
               __hip_bfloat16* __restrict__ Wt_h) {
  const int z = blockIdx.z;
  if (z != 1 && blockIdx.x >= 16) return;
  const int K = (z == 1) ? 1024 : 512;
  const float* W = (z == 0) ? W_t : ((z == 1) ? W_j : W_h);
  __hip_bfloat16* Wt = (z == 0) ? Wt_t : ((z == 1) ? Wt_j : Wt_h);
  __shared__ float sh[32][33];
  const int tx = threadIdx.x & 31, ty = threadIdx.x >> 5;
  const int k0 = blockIdx.x * 32, n0 = blockIdx.y * 32;
#pragma unroll
  for (int i = 0; i < 4; ++i)
    sh[ty + i * 8][tx] = W[(size_t)(k0 + ty + i * 8) * 512 + n0 + tx];
  __syncthreads();
#pragma unroll
  for (int i = 0; i < 4; ++i)
    Wt[(size_t)(n0 + ty + i * 8) * K + k0 + tx] = __float2bfloat16(sh[tx][ty + i * 8]);
}

// ---------- bf16 MFMA GEMM: C = epi(A[M,K] @ Bt^T), N=512 ----------
// AFP32: A fp32, converted to bf16 during LDS staging.
// MODE 0: relu -> bf16 Cb.
// MODE 1: write-stage epilogue -> fp32 Cf (reads chp 4-partials, ctrlT, raw upd).
template<int MODE, bool AFP32>
__global__ __launch_bounds__(256)
void mfma_gemm(const __hip_bfloat16* __restrict__ A, const float* __restrict__ Af,
               const __hip_bfloat16* __restrict__ Bt, int M, int K,
               __hip_bfloat16* __restrict__ Cb, float* __restrict__ Cf,
               const float* __restrict__ chp, const float* __restrict__ ctrlT,
               const float* __restrict__ attn, const float* __restrict__ upd_raw,
               const __hip_bfloat16* __restrict__ leaf) {
  __shared__ __align__(16) __hip_bfloat16 Asm[128 * 32];
  __shared__ __align__(16) __hip_bfloat16 Bsm[128 * 32];
  __shared__ float ch_sh[128];
  const int tid = threadIdx.x;
  const int wave = tid >> 6, lane = tid & 63;
  const int bm = blockIdx.y * 128, bn = blockIdx.x * 128;
  const int wm = (wave >> 1) * 64, wn = (wave & 1) * 64;
  const int q = lane >> 4, lr = lane & 15;
  const int bidx = bm >> 8;   // one batch per 128-row tile

  if (MODE == 1 && tid < 128) {
    ch_sh[tid] = chp[(size_t)(0 * 64 + bidx) * 512 + bn + tid]
               + chp[(size_t)(1 * 64 + bidx) * 512 + bn + tid]
               + chp[(size_t)(2 * 64 + bidx) * 512 + bn + tid]
               + chp[(size_t)(3 * 64 + bidx) * 512 + bn + tid];
  }

  f32x4 acc[4][4] = {};

  const int c0 = wave * 128 + lane, c1 = c0 + 64;
  const size_t ga0 = (size_t)(bm + (c0 >> 2)) * K + (c0 & 3) * 8;
  const size_t ga1 = (size_t)(bm + (c1 >> 2)) * K + (c1 & 3) * 8;
  const size_t gb0 = (size_t)(bn + (c0 >> 2)) * K + (c0 & 3) * 8;
  const size_t gb1 = (size_t)(bn + (c1 >> 2)) * K + (c1 & 3) * 8;
  __hip_bfloat16* la0 = Asm + wave * 1024;
  __hip_bfloat16* la1 = Asm + wave * 1024 + 512;
  __hip_bfloat16* lb0 = Bsm + wave * 1024;
  __hip_bfloat16* lb1 = Bsm + wave * 1024 + 512;

  for (int k0v = 0; k0v < K; k0v += 32) {
    if (AFP32) {
#pragma unroll
      for (int it = 0; it < 4; ++it) {
        const int c = it * 256 + tid;
        const int row = c >> 3, kc = c & 7;
        float4 v = *(const float4*)(Af + (size_t)(bm + row) * K + k0v + kc * 4);
        __hip_bfloat16 h[4] = {__float2bfloat16(v.x), __float2bfloat16(v.y),
                               __float2bfloat16(v.z), __float2bfloat16(v.w)};
        *(ushort4*)(Asm + row * 32 + kc * 4) = *(ushort4*)h;
      }
    } else {
      load_lds16b(A + ga0 + k0v, la0);
      load_lds16b(A + ga1 + k0v, la1);
    }
    load_lds16b(Bt + gb0 + k0v, lb0);
    load_lds16b(Bt + gb1 + k0v, lb1);
    __syncthreads();
    bf16x8 af[4], bfr[4];
#pragma unroll
    for (int mt = 0; mt < 4; ++mt)
      af[mt] = *(const bf16x8*)(Asm + (wm + mt * 16 + lr) * 32 + q * 8);
#pragma unroll
    for (int nt = 0; nt < 4; ++nt)
      bfr[nt] = *(const bf16x8*)(Bsm + (wn + nt * 16 + lr) * 32 + q * 8);
#pragma unroll
    for (int mt = 0; mt < 4; ++mt)
#pragma unroll
      for (int nt = 0; nt < 4; ++nt)
        acc[mt][nt] = __builtin_amdgcn_mfma_f32_16x16x32_bf16(af[mt], bfr[nt], acc[mt][nt], 0, 0, 0);
    __syncthreads();
  }

  // C/D layout: col = lane&15, row = (lane>>4)*4 + reg
  if (MODE == 0) {
#pragma unroll
    for (int mt = 0; mt < 4; ++mt) {
      const int rbase = bm + wm + mt * 16 + q * 4;
#pragma unroll
      for (int nt = 0; nt < 4; ++nt) {
        const int col = bn + wn + nt * 16 + lr;
#pragma unroll
        for (int r = 0; r < 4; ++r) {
          const int row = rbase + r;
          if (row < M)
            Cb[(size_t)row * 512 + col] = __float2bfloat16(fmaxf(acc[mt][nt][r], 0.f));
        }
      }
    }
  } else {
    const float cT = ctrlT[bidx];
#pragma unroll
    for (int mt = 0; mt < 4; ++mt) {
      const int rbase = bm + wm + mt * 16 + q * 4;
#pragma unroll
      for (int r = 0; r < 4; ++r) {
        const int row = rbase + r;
        const float a = attn[row];
        const float u = sigmoidf_(upd_raw[row] + cT);
#pragma unroll
        for (int nt = 0; nt < 4; ++nt) {
          const int col = bn + wn + nt * 16 + lr;
          const float cand = sigmoidf_(acc[mt][nt][r] + ch_sh[wn + nt * 16 + lr]);
          const float lf = __bfloat162float(leaf[(size_t)row * 512 + col]);
          const float w = u * cand + (1.f - u) * lf;
          Cf[(size_t)row * 512 + col] = a * w + (1.f - a) * lf;
        }
      }
    }
  }
}

// ---------- fused join levels 4..8: one block per batch ----------
// Level l-1 output (m_in rows x 512) lives in LDS; pairs of rows form the
// 1024-wide A rows. B streamed from L2-resident Wt_j. A is read once per
// k-step and reused across the wave's 8 n-tiles.
__global__ __launch_bounds__(256)
void join_tail45678(const __hip_bfloat16* __restrict__ lvl3,
                    __hip_bfloat16* __restrict__ levels,
                    const __hip_bfloat16* __restrict__ Wt_j) {
  constexpr int STR = 520;                       // bf16; 1040 B rows (16B aligned)
  __shared__ __align__(16) __hip_bfloat16 bufA[32 * STR];
  __shared__ __align__(16) __hip_bfloat16 bufB[16 * STR];
  const int b = blockIdx.x;
  const int tid = threadIdx.x;
  const int wave = tid >> 6, lane = tid & 63;
  const int q = lane >> 4, lr = lane & 15;

  // load level-3 (32 rows x 512) into bufA
  {
    const __hip_bfloat16* src = lvl3 + (size_t)b * 32 * 512;
    for (int i = tid; i < 32 * 64; i += 256) {
      const int r = i >> 6, c = i & 63;
      *(bf16x8*)(bufA + r * STR + c * 8) = *(const bf16x8*)(src + (size_t)r * 512 + c * 8);
    }
  }
  __syncthreads();

  const size_t off_e[9] = {0, 0, 4194304, 6291456, 7340032,
                           7864320, 8126464, 8257536, 8323072};
  __hip_bfloat16* cur = bufA;
  __hip_bfloat16* nxt = bufB;
  int m_out = 16;
  for (int l = 4; l <= 8; ++l, m_out >>= 1) {
    const int arow = (lr < m_out) ? lr : 0;
    f32x4 acc[8] = {};
    for (int k0 = 0; k0 < 1024; k0 += 32) {
      const int kk = k0 + q * 8;
      const bf16x8 a = *(const bf16x8*)(cur + (2 * arow + (kk >> 9)) * STR + (kk & 511));
#pragma unroll
      for (int j = 0; j < 8; ++j) {
        const bf16x8 bb = *(const bf16x8*)(Wt_j + (size_t)((wave * 8 + j) * 16 + lr) * 1024 + kk);
        acc[j] = __builtin_amdgcn_mfma_f32_16x16x32_bf16(a, bb, acc[j], 0, 0, 0);
      }
    }
    __hip_bfloat16* gout = levels + off_e[l] + (size_t)b * m_out * 512;
#pragma unroll
    for (int j = 0; j < 8; ++j) {
      const int col = (wave * 8 + j) * 16 + lr;
#pragma unroll
      for (int r = 0; r < 4; ++r) {
        const int row = q * 4 + r;
        if (row < m_out) {
          const __hip_bfloat16 v = __float2bfloat16(fmaxf(acc[j][r], 0.f));
          nxt[row * STR + col] = v;
          gout[(size_t)row * 512 + col] = v;
        }
      }
    }
    __syncthreads();
    __hip_bfloat16* t = cur; cur = nxt; nxt = t;
  }
}

// ---------- fused GEMV: raw upd dots (4096 blocks) + node scores (4080) ----------
__global__ __launch_bounds__(256)
void gemv_dual(const __hip_bfloat16* __restrict__ leaf,
               const __hip_bfloat16* __restrict__ levels,
               const float* __restrict__ W_T, const float* __restrict__ W_s,
               float* __restrict__ upd_raw, float* __restrict__ sc) {
  const int wave = threadIdx.x >> 6, lane = threadIdx.x & 63;
  const int bid = blockIdx.x;
  const bool is_upd = bid < 4096;
  const int row = (is_upd ? bid : (bid - 4096)) * 4 + wave;
  const __hip_bfloat16* X = is_upd ? leaf : levels;
  const float* w = is_upd ? W_T : W_s;
  union { bf16x8 v; __hip_bfloat16 e[8]; } u;
  u.v = *(const bf16x8*)(X + (size_t)row * 512 + lane * 8);
  const float* wp = w + lane * 8;
  float p = 0.f;
#pragma unroll
  for (int j = 0; j < 8; ++j) p += __bfloat162float(u.e[j]) * wp[j];
#pragma unroll
  for (int off = 32; off > 0; off >>= 1) p += __shfl_down(p, off);
  if (lane == 0) {
    if (is_upd) upd_raw[row] = p;
    else        sc[row] = p;
  }
}

// ---------- ctrl_h split-K + ctrlT ----------
__global__ __launch_bounds__(256)
void ctrl_gemm(const float* __restrict__ h0, const float* __restrict__ W_h,
               const float* __restrict__ W_T,
               float* __restrict__ chp, float* __restrict__ ctrlT) {
  const int col = blockIdx.x * 256 + threadIdx.x;
  const int b   = blockIdx.y;
  const int z   = blockIdx.z;
  __shared__ float hsh[128];
  __shared__ float part[256];
  if (threadIdx.x < 128) hsh[threadIdx.x] = h0[b * 512 + z * 128 + threadIdx.x];
  __syncthreads();
  const float* Wp = W_h + (size_t)(512 + z * 128) * 512 + col;
  float s = 0.f;
#pragma unroll 8
  for (int k = 0; k < 128; ++k) s += hsh[k] * Wp[(size_t)k * 512];
  chp[((size_t)z * 64 + b) * 512 + col] = s;

  if (z == 0 && blockIdx.x == 0) {   // ctrlT[b] = h0[b,:].W_T[512:]
    const int tid = threadIdx.x;
    float p2 = 0.f;
    for (int i = tid; i < 512; i += 256) p2 += h0[b * 512 + i] * W_T[512 + i];
    part[tid] = p2; __syncthreads();
    for (int st = 128; st > 0; st >>= 1) { if (tid < st) part[tid] += part[tid + st]; __syncthreads(); }
    if (tid == 0) ctrlT[b] = part[0];
  }
}

// ---------- attention propagate + tree_out, one block per batch ----------
__global__ __launch_bounds__(256)
void propagate_tree(const float* __restrict__ sc, const float* __restrict__ h0,
                    const float* __restrict__ W_s, const float* __restrict__ inputs,
                    float* __restrict__ attn_out, float* __restrict__ tre) {
  const int b = blockIdx.x, tid = threadIdx.x;
  __shared__ float part[256], attn_sh[256], newattn[256];
  __shared__ float scs;
  float p = 0.f;
  for (int i = tid; i < 512; i += 256) p += h0[b * 512 + i] * W_s[512 + i];
  part[tid] = p; __syncthreads();
  for (int s = 128; s > 0; s >>= 1) { if (tid < s) part[tid] += part[tid + s]; __syncthreads(); }
  if (tid == 0) { scs = part[0]; attn_sh[0] = 1.f; }
  __syncthreads();
  const int row_off[9] = {0, 0, 8192, 12288, 14336, 15360, 15872, 16128, 16256};
#pragma unroll
  for (int l = 8; l >= 1; --l) {
    const int m = 256 >> l;
    if (tid < m) {
      const float mr = sigmoidf_(sc[row_off[l] + b * m + tid] + scs);
      const float a = attn_sh[tid];
      newattn[2 * tid]     = a * (1.f - mr);
      newattn[2 * tid + 1] = a * mr;
    }
    __syncthreads();
    if (tid < 2 * m) attn_sh[tid] = newattn[tid];
    __syncthreads();
  }
  attn_out[b * 256 + tid] = attn_sh[tid];

  // tree_out[b,e] = sum_n attn[n] * inputs[b,n,e]
  float acc0 = 0.f, acc1 = 0.f;
  const float* base = inputs + (size_t)b * 256 * 512;
#pragma unroll 4
  for (int n = 0; n < 256; ++n) {
    const float a = attn_sh[n];
    acc0 += a * base[(size_t)n * 512 + tid];
    acc1 += a * base[(size_t)n * 512 + tid + 256];
  }
  tre[b * 512 + tid]       = acc0;
  tre[b * 512 + tid + 256] = acc1;
}

// ---------- LSTM split-K ----------
__global__ __launch_bounds__(256)
void lstm_gemm_splitk(const float* __restrict__ tre, const float* __restrict__ h0,
                      const float* __restrict__ kern, const float* __restrict__ rec,
                      float* __restrict__ Zp) {
  const int tid = threadIdx.x;
  const int col = blockIdx.x * 256 + tid;
  const int b0 = blockIdx.y * 4;
  const int z = blockIdx.z;
  const float* X = (z < 4) ? tre : h0;
  const float* W = (z < 4) ? (kern + (size_t)z * 128 * 2048)
                           : (rec + (size_t)(z - 4) * 128 * 2048);
  const int koff = (z & 3) * 128;
  __shared__ float xs[4][128];
  for (int i = tid; i < 512; i += 256) {
    int bb = i >> 7, k = i & 127;
    xs[bb][k] = X[(b0 + bb) * 512 + koff + k];
  }
  __syncthreads();
  float a0 = 0.f, a1 = 0.f, a2 = 0.f, a3 = 0.f;
#pragma unroll 8
  for (int k = 0; k < 128; ++k) {
    const float w = W[(size_t)k * 2048 + col];
    a0 += xs[0][k] * w;
    a1 += xs[1][k] * w;
    a2 += xs[2][k] * w;
    a3 += xs[3][k] * w;
  }
  Zp[((size_t)z * 64 + b0 + 0) * 2048 + col] = a0;
  Zp[((size_t)z * 64 + b0 + 1) * 2048 + col] = a1;
  Zp[((size_t)z * 64 + b0 + 2) * 2048 + col] = a2;
  Zp[((size_t)z * 64 + b0 + 3) * 2048 + col] = a3;
}

__global__ __launch_bounds__(256)
void lstm_combine(const float* __restrict__ Zp, const float* __restrict__ bias,
                  const float* __restrict__ c0,
                  float* __restrict__ out_h, float* __restrict__ out_c) {
  const int i = blockIdx.x * 256 + threadIdx.x;
  const int b = i >> 9, u = i & 511;
  float zi = bias[u], zf = bias[512 + u], zg = bias[1024 + u], zo = bias[1536 + u];
#pragma unroll
  for (int z = 0; z < 8; ++z) {
    const size_t base = ((size_t)z * 64 + b) * 2048;
    zi += Zp[base + u];
    zf += Zp[base + 512 + u];
    zg += Zp[base + 1024 + u];
    zo += Zp[base + 1536 + u];
  }
  const float c = sigmoidf_(zf) * c0[i] + sigmoidf_(zi) * tanhf(zg);
  out_h[i] = sigmoidf_(zo) * tanhf(c);
  out_c[i] = c;
}

extern "C" void kernel_launch(void* const* d_in, const int* in_sizes, int n_in,
                              void* d_out, int out_size, void* d_ws, size_t ws_size,
                              hipStream_t stream) {
  const float* inputs = (const float*)d_in[0];
  const float* h0     = (const float*)d_in[1];
  const float* c0     = (const float*)d_in[2];
  const float* W_t    = (const float*)d_in[3];
  const float* W_j    = (const float*)d_in[4];
  const float* W_s    = (const float*)d_in[5];
  const float* W_h    = (const float*)d_in[6];
  const float* W_T    = (const float*)d_in[7];
  const float* kern   = (const float*)d_in[8];
  const float* rec    = (const float*)d_in[9];
  const float* bias   = (const float*)d_in[10];
  float* out = (float*)d_out;

  char* p = (char*)d_ws;
  __hip_bfloat16* leaf_bf   = (__hip_bfloat16*)p; p += 16777216;   // 16384x512
  __hip_bfloat16* levels_bf = (__hip_bfloat16*)p; p += 16842752;   // 16320x512 + pad
  __hip_bfloat16* Wt_t      = (__hip_bfloat16*)p; p += 524288;
  __hip_bfloat16* Wt_j      = (__hip_bfloat16*)p; p += 1048576;
  __hip_bfloat16* Wt_h      = (__hip_bfloat16*)p; p += 524288;
  float* attn  = (float*)p; p += 65536;    // 64x256
  float* updr  = (float*)p; p += 65536;    // 64x256 raw dots
  float* tre   = (float*)p; p += 131072;   // 64x512
  float* chp   = (float*)p; p += 524288;   // 4x64x512 partials
  float* Zp    = (float*)p; p += 4194304;  // 8x64x2048
  float* sc    = (float*)p; p += 65536;    // 16320 node scores (+pad)
  float* ctrlT = (float*)p; p += 4096;     // 64

  const int lvl_off_h[9] = {0, 0, 4194304, 6291456, 7340032,
                            7864320, 8126464, 8257536, 8323072};

  // 1. weight prep + control projections
  tconv_all<<<dim3(32, 16, 3), 256, 0, stream>>>(W_t, W_j, W_h, Wt_t, Wt_j, Wt_h);
  ctrl_gemm<<<dim3(2, 64, 4), 256, 0, stream>>>(h0, W_h, W_T, chp, ctrlT);

  // 2. leaf embed (fused fp32->bf16 staging)
  mfma_gemm<0, true><<<dim3(4, 128), 256, 0, stream>>>(
      nullptr, inputs, Wt_t, 16384, 512, leaf_bf, nullptr,
      nullptr, nullptr, nullptr, nullptr, nullptr);

  // 3. join levels 1..3 (tiled MFMA GEMMs)
  const __hip_bfloat16* Aptr = leaf_bf;
  for (int l = 1; l <= 3; ++l) {
    const int M = 64 * (256 >> l);
    __hip_bfloat16* Cl = levels_bf + lvl_off_h[l];
    mfma_gemm<0, false><<<dim3(4, M / 128), 256, 0, stream>>>(
        Aptr, nullptr, Wt_j, M, 1024, Cl, nullptr,
        nullptr, nullptr, nullptr, nullptr, nullptr);
    Aptr = Cl;
  }
  // 4. levels 4..8 fused
  join_tail45678<<<64, 256, 0, stream>>>(levels_bf + lvl_off_h[3], levels_bf, Wt_j);

  // 5. raw upd dots + node scores, then attention + tree_out
  gemv_dual<<<8176, 256, 0, stream>>>(leaf_bf, levels_bf, W_T, W_s, updr, sc);
  propagate_tree<<<64, 256, 0, stream>>>(sc, h0, W_s, inputs, attn, tre);

  // 6. write stage -> leaf_h_new (fp32) at out[65536:]
  mfma_gemm<1, false><<<dim3(4, 128), 256, 0, stream>>>(
      leaf_bf, nullptr, Wt_h, 16384, 512, nullptr, out + 65536,
      chp, ctrlT, attn, updr, leaf_bf);

  // 7. LSTM
  lstm_gemm_splitk<<<dim3(8, 16, 8), 256, 0, stream>>>(tre, h0, kern, rec, Zp);
  lstm_combine<<<128, 256, 0, stream>>>(Zp, bias, c0, out, out + 32768);
}